// Round 1
// baseline (16196.602 us; speedup 1.0000x reference)
//
#include <hip/hip_runtime.h>
#include <hip/hip_bf16.h>
#include <stdint.h>

#define T_STEPS 512
#define BATCH   64
#define HID     512
#define DIN     512
#define G4      2048   // 4*HID

typedef __attribute__((ext_vector_type(8))) short bf16x8;
typedef __attribute__((ext_vector_type(4))) float f32x4;
typedef __attribute__((ext_vector_type(4))) unsigned short us4;

static __device__ __forceinline__ unsigned short f2bf(float f) {
  union { float f; unsigned u; } v; v.f = f;
  unsigned r = v.u + 0x7FFFu + ((v.u >> 16) & 1u);  // round-to-nearest-even
  return (unsigned short)(r >> 16);
}
static __device__ __forceinline__ float bf2f(unsigned short s) {
  union { unsigned u; float f; } v; v.u = ((unsigned)s) << 16;
  return v.f;
}
static __device__ __forceinline__ float sigf(float x) { return 1.f / (1.f + __expf(-x)); }
static __device__ __forceinline__ float tanh_fast(float x) {
  x = fminf(15.f, fmaxf(-15.f, x));
  float e = __expf(2.f * x);
  return (e - 1.f) / (e + 1.f);
}

__global__ void cvt_f32_bf16(const float* __restrict__ src, unsigned short* __restrict__ dst, long n) {
  long i = (long)blockIdx.x * blockDim.x + threadIdx.x;
  long st = (long)gridDim.x * blockDim.x;
  for (; i < n; i += st) dst[i] = f2bf(src[i]);
}

__global__ void bias_sum(const float* __restrict__ a, const float* __restrict__ b,
                         float* __restrict__ o, int n) {
  int i = blockIdx.x * blockDim.x + threadIdx.x;
  if (i < n) o[i] = a[i] + b[i];
}

// xg[t][g][b] = sum_k IN(b,t,k) * W[g][k] + bias[g]
// IN is bf16 with element addressing IN[b*strideB + t*strideT + k].
// MFMA: A = W rows (M=g), B = IN (N=b), K=512.
__global__ __launch_bounds__(256) void proj_kernel(
    const unsigned short* __restrict__ IN, long strideB, long strideT,
    const unsigned short* __restrict__ Wb, const float* __restrict__ bias,
    unsigned short* __restrict__ xg) {
  const int gtile = blockIdx.x;        // 0..31
  const int t     = blockIdx.y;        // 0..511
  const int wave  = threadIdx.x >> 6;  // 0..3
  const int lane  = threadIdx.x & 63;
  const int n16   = lane & 15;
  const int kof   = (lane >> 4) * 8;
  const int g0    = gtile * 64 + wave * 16;

  const unsigned short* ap  = Wb + (long)(g0 + n16) * DIN + kof;
  const unsigned short* bp0 = IN + (long)(n16 +  0) * strideB + (long)t * strideT + kof;
  const unsigned short* bp1 = IN + (long)(n16 + 16) * strideB + (long)t * strideT + kof;
  const unsigned short* bp2 = IN + (long)(n16 + 32) * strideB + (long)t * strideT + kof;
  const unsigned short* bp3 = IN + (long)(n16 + 48) * strideB + (long)t * strideT + kof;

  f32x4 acc0 = {0.f,0.f,0.f,0.f}, acc1 = {0.f,0.f,0.f,0.f};
  f32x4 acc2 = {0.f,0.f,0.f,0.f}, acc3 = {0.f,0.f,0.f,0.f};
  #pragma unroll
  for (int kk = 0; kk < 16; ++kk) {
    bf16x8 a  = *(const bf16x8*)(ap  + kk * 32);
    bf16x8 b0 = *(const bf16x8*)(bp0 + kk * 32);
    bf16x8 b1 = *(const bf16x8*)(bp1 + kk * 32);
    bf16x8 b2 = *(const bf16x8*)(bp2 + kk * 32);
    bf16x8 b3 = *(const bf16x8*)(bp3 + kk * 32);
    acc0 = __builtin_amdgcn_mfma_f32_16x16x32_bf16(a, b0, acc0, 0, 0, 0);
    acc1 = __builtin_amdgcn_mfma_f32_16x16x32_bf16(a, b1, acc1, 0, 0, 0);
    acc2 = __builtin_amdgcn_mfma_f32_16x16x32_bf16(a, b2, acc2, 0, 0, 0);
    acc3 = __builtin_amdgcn_mfma_f32_16x16x32_bf16(a, b3, acc3, 0, 0, 0);
  }
  const int m0 = (lane >> 4) * 4;
  #pragma unroll
  for (int r = 0; r < 4; ++r) {
    const int g = g0 + m0 + r;
    const float bv = bias[g];
    long base = ((long)t * G4 + g) * BATCH + n16;
    xg[base +  0] = f2bf(acc0[r] + bv);
    xg[base + 16] = f2bf(acc1[r] + bv);
    xg[base + 32] = f2bf(acc2[r] + bv);
    xg[base + 48] = f2bf(acc3[r] + bv);
  }
}

// Persistent recurrence. 256 WGs x 64 threads (1 wave each).
// Group gq = blockIdx&3 owns batches [gq*16, gq*16+16); member j = blockIdx>>2
// owns hidden [j*8, j*8+8) i.e. 32 gate rows {f,i,g,o} x 8 hids, Wh slice in LDS.
// Row order r in [0,32): gate = r>>3 (0=f,1=i,2=g,3=o), hid = r&7.
//   tile0 (rows 0..15)  = f(0..7), i(0..7)
//   tile1 (rows 16..31) = g(0..7), o(0..7)
// Per step: MFMA (M=16 batches, N=32 rows, K=512) + xg add + shfl_xor(8)
// gate exchange + fp32 cell update; h written bf16 to double-buffered hx;
// flag barrier among the 64 group members (one wave-wide flag load).
__global__ __launch_bounds__(64) void rec_kernel(
    const unsigned short* __restrict__ Whb,   // [2048][512] bf16
    const unsigned short* __restrict__ xg,    // [T][2048][64] bf16
    unsigned short* __restrict__ hx,          // [2][64][512] bf16 (this layer)
    int* __restrict__ flags,                  // [4][64] (this layer)
    unsigned short* __restrict__ hseq,        // [T][64][512] bf16 or null
    float* __restrict__ out,                  // [64][512] or null
    int T) {
  __shared__ unsigned short whl[32 * 512];    // 32 KB, XOR-swizzled
  const int bid  = blockIdx.x;
  const int gq   = bid & 3;
  const int j    = bid >> 2;                  // 0..63
  const int lane = threadIdx.x;               // 0..63
  const int hidbase = j * 8;
  const int n16  = lane & 15;
  const int kof  = (lane >> 4) * 8;

  // ---- load Wh slice into LDS (swizzle byte col ^ ((r&7)<<4)) ----
  #pragma unroll 4
  for (int r = 0; r < 32; ++r) {
    const int gate = r >> 3;
    const long grow = (long)gate * HID + hidbase + (r & 7);
    bf16x8 v = *(const bf16x8*)(Whb + grow * HID + lane * 8);
    const int byteoff = r * 1024 + ((lane * 16) ^ ((r & 7) << 4));
    *(bf16x8*)((char*)whl + byteoff) = v;
  }
  __syncthreads();

  float c0 = 0.f, c1 = 0.f, c2 = 0.f, c3 = 0.f;  // cell state (lanes n16<8)
  const int* gflags = flags + gq * 64;

  for (int t = 0; t < T; ++t) {
    const int par = t & 1;
    if (t > 0) {
      int v;
      do {
        v = __hip_atomic_load(&gflags[lane], __ATOMIC_RELAXED, __HIP_MEMORY_SCOPE_AGENT);
      } while (__any(v < t));
      __threadfence();  // acquire: see peers' h writes, invalidate stale L1
    }

    // xg slice for this step (independent of h -> issue early)
    const int rr0 = n16, rr1 = 16 + n16;
    const int grow0 = (rr0 >> 3) * HID + hidbase + (rr0 & 7);
    const int grow1 = (rr1 >> 3) * HID + hidbase + (rr1 & 7);
    const int bloc = (lane >> 4) * 4;
    us4 xv0 = *(const us4*)(xg + ((long)t * G4 + grow0) * BATCH + gq * 16 + bloc);
    us4 xv1 = *(const us4*)(xg + ((long)t * G4 + grow1) * BATCH + gq * 16 + bloc);

    // ---- gates = h @ Wh^T ----
    const unsigned short* hp = hx + ((long)par * BATCH + gq * 16 + n16) * HID + kof;
    f32x4 acc0 = {0.f,0.f,0.f,0.f}, acc1 = {0.f,0.f,0.f,0.f};
    #pragma unroll
    for (int kk = 0; kk < 16; ++kk) {
      bf16x8 a = *(const bf16x8*)(hp + kk * 32);
      const int colb = (kof + kk * 32) * 2;
      const int by0 = rr0 * 1024 + (colb ^ ((rr0 & 7) << 4));
      const int by1 = rr1 * 1024 + (colb ^ ((rr1 & 7) << 4));
      bf16x8 b0 = *(const bf16x8*)((const char*)whl + by0);
      bf16x8 b1 = *(const bf16x8*)((const char*)whl + by1);
      acc0 = __builtin_amdgcn_mfma_f32_16x16x32_bf16(a, b0, acc0, 0, 0, 0);
      acc1 = __builtin_amdgcn_mfma_f32_16x16x32_bf16(a, b1, acc1, 0, 0, 0);
    }
    #pragma unroll
    for (int r = 0; r < 4; ++r) {
      acc0[r] += bf2f(xv0[r]);
      acc1[r] += bf2f(xv1[r]);
    }

    // exchange with partner lane (n16 ^ 8): pairs (f,g) <-> (i,o)
    f32x4 o0, o1;
    #pragma unroll
    for (int r = 0; r < 4; ++r) {
      o0[r] = __shfl_xor(acc0[r], 8, 64);
      o1[r] = __shfl_xor(acc1[r], 8, 64);
    }

    if (n16 < 8) {
      const int hid = hidbase + n16;
      float cc[4] = {c0, c1, c2, c3};
      #pragma unroll
      for (int r = 0; r < 4; ++r) {
        const float fg = sigf(acc0[r]);      // f
        const float ig = sigf(o0[r]);        // i
        const float gg = tanh_fast(acc1[r]); // g
        const float og = sigf(o1[r]);        // o
        const float cn = fg * cc[r] + ig * gg;
        cc[r] = cn;
        const float h = og * tanh_fast(cn);
        const unsigned short hb = f2bf(h);
        const int brow = gq * 16 + bloc + r;
        hx[((long)(par ^ 1) * BATCH + brow) * HID + hid] = hb;
        if (hseq) hseq[((long)t * BATCH + brow) * HID + hid] = hb;
        if (out && t == T - 1) out[(long)brow * HID + hid] = h;
      }
      c0 = cc[0]; c1 = cc[1]; c2 = cc[2]; c3 = cc[3];
    }

    __threadfence();  // release: h writes visible before flag
    if (lane == 0)
      __hip_atomic_store(&flags[gq * 64 + j], t + 1, __ATOMIC_RELAXED, __HIP_MEMORY_SCOPE_AGENT);
  }
}

extern "C" void kernel_launch(void* const* d_in, const int* in_sizes, int n_in,
                              void* d_out, int out_size, void* d_ws, size_t ws_size,
                              hipStream_t stream) {
  const float* x   = (const float*)d_in[0];
  const float* Wx0 = (const float*)d_in[1];
  const float* bx0 = (const float*)d_in[2];
  const float* Wh0 = (const float*)d_in[3];
  const float* bh0 = (const float*)d_in[4];
  const float* Wx1 = (const float*)d_in[5];
  const float* bx1 = (const float*)d_in[6];
  const float* Wh1 = (const float*)d_in[7];
  const float* bh1 = (const float*)d_in[8];

  char* ws = (char*)d_ws;
  size_t off = 0;
  auto alloc = [&](size_t bytes) -> char* {
    char* p = ws + off; off += (bytes + 255) & ~(size_t)255; return p;
  };
  unsigned short* xg   = (unsigned short*)alloc((size_t)T_STEPS * G4 * BATCH * 2);   // 128 MiB
  unsigned short* xb   = (unsigned short*)alloc((size_t)BATCH * T_STEPS * DIN * 2);  // 32 MiB
  unsigned short* hseq = (unsigned short*)alloc((size_t)T_STEPS * BATCH * HID * 2);  // 32 MiB
  unsigned short* Wx0b = (unsigned short*)alloc((size_t)G4 * DIN * 2);
  unsigned short* Wh0b = (unsigned short*)alloc((size_t)G4 * HID * 2);
  unsigned short* Wx1b = (unsigned short*)alloc((size_t)G4 * HID * 2);
  unsigned short* Wh1b = (unsigned short*)alloc((size_t)G4 * HID * 2);
  float* bs0 = (float*)alloc((size_t)G4 * 4);
  float* bs1 = (float*)alloc((size_t)G4 * 4);
  char* zbase = ws + off;  // everything below gets zeroed each call
  unsigned short* hx0 = (unsigned short*)alloc((size_t)2 * BATCH * HID * 2);
  unsigned short* hx1 = (unsigned short*)alloc((size_t)2 * BATCH * HID * 2);
  int* flags0 = (int*)alloc(4 * 64 * 4);
  int* flags1 = (int*)alloc(4 * 64 * 4);
  size_t zbytes = (size_t)((ws + off) - zbase);

  hipMemsetAsync(zbase, 0, zbytes, stream);

  // bf16 conversions + bias sums
  cvt_f32_bf16<<<1024, 256, 0, stream>>>(Wx0, Wx0b, (long)G4 * DIN);
  cvt_f32_bf16<<<1024, 256, 0, stream>>>(Wh0, Wh0b, (long)G4 * HID);
  cvt_f32_bf16<<<1024, 256, 0, stream>>>(Wx1, Wx1b, (long)G4 * HID);
  cvt_f32_bf16<<<1024, 256, 0, stream>>>(Wh1, Wh1b, (long)G4 * HID);
  cvt_f32_bf16<<<4096, 256, 0, stream>>>(x, xb, (long)BATCH * T_STEPS * DIN);
  bias_sum<<<8, 256, 0, stream>>>(bx0, bh0, bs0, G4);
  bias_sum<<<8, 256, 0, stream>>>(bx1, bh1, bs1, G4);

  dim3 pg(32, T_STEPS);
  // layer 0: IN = xb [B][T][D]  -> strideB = T*D, strideT = D
  proj_kernel<<<pg, 256, 0, stream>>>(xb, (long)T_STEPS * DIN, (long)DIN, Wx0b, bs0, xg);
  rec_kernel<<<256, 64, 0, stream>>>(Wh0b, xg, hx0, flags0, hseq, nullptr, T_STEPS);
  // layer 1: IN = hseq [T][B][H] -> strideB = H, strideT = B*H
  proj_kernel<<<pg, 256, 0, stream>>>(hseq, (long)HID, (long)BATCH * HID, Wx1b, bs1, xg);
  rec_kernel<<<256, 64, 0, stream>>>(Wh1b, xg, hx1, flags1, nullptr, (float*)d_out, T_STEPS);
}

// Round 2
// 6748.349 us; speedup vs baseline: 2.4001x; 2.4001x over previous
//
#include <hip/hip_runtime.h>
#include <hip/hip_bf16.h>
#include <stdint.h>

#define T_STEPS 512
#define BATCH   64
#define HID     512
#define DIN     512
#define G4      2048   // 4*HID

typedef __attribute__((ext_vector_type(8))) short bf16x8;
typedef __attribute__((ext_vector_type(4))) float f32x4;
typedef __attribute__((ext_vector_type(4))) unsigned short us4;

static __device__ __forceinline__ unsigned short f2bf(float f) {
  union { float f; unsigned u; } v; v.f = f;
  unsigned r = v.u + 0x7FFFu + ((v.u >> 16) & 1u);  // round-to-nearest-even
  return (unsigned short)(r >> 16);
}
static __device__ __forceinline__ float bf2f(unsigned short s) {
  union { unsigned u; float f; } v; v.u = ((unsigned)s) << 16;
  return v.f;
}
static __device__ __forceinline__ float sigf(float x) { return 1.f / (1.f + __expf(-x)); }
static __device__ __forceinline__ float tanh_fast(float x) {
  x = fminf(15.f, fmaxf(-15.f, x));
  float e = __expf(2.f * x);
  return (e - 1.f) / (e + 1.f);
}

__global__ void cvt_f32_bf16(const float* __restrict__ src, unsigned short* __restrict__ dst, long n) {
  long i = (long)blockIdx.x * blockDim.x + threadIdx.x;
  long st = (long)gridDim.x * blockDim.x;
  for (; i < n; i += st) dst[i] = f2bf(src[i]);
}

__global__ void bias_sum(const float* __restrict__ a, const float* __restrict__ b,
                         float* __restrict__ o, int n) {
  int i = blockIdx.x * blockDim.x + threadIdx.x;
  if (i < n) o[i] = a[i] + b[i];
}

// xg[t][g][b] = sum_k IN(b,t,k) * W[g][k] + bias[g]
__global__ __launch_bounds__(256) void proj_kernel(
    const unsigned short* __restrict__ IN, long strideB, long strideT,
    const unsigned short* __restrict__ Wb, const float* __restrict__ bias,
    unsigned short* __restrict__ xg) {
  const int gtile = blockIdx.x;        // 0..31
  const int t     = blockIdx.y;        // 0..511
  const int wave  = threadIdx.x >> 6;  // 0..3
  const int lane  = threadIdx.x & 63;
  const int n16   = lane & 15;
  const int kof   = (lane >> 4) * 8;
  const int g0    = gtile * 64 + wave * 16;

  const unsigned short* ap  = Wb + (long)(g0 + n16) * DIN + kof;
  const unsigned short* bp0 = IN + (long)(n16 +  0) * strideB + (long)t * strideT + kof;
  const unsigned short* bp1 = IN + (long)(n16 + 16) * strideB + (long)t * strideT + kof;
  const unsigned short* bp2 = IN + (long)(n16 + 32) * strideB + (long)t * strideT + kof;
  const unsigned short* bp3 = IN + (long)(n16 + 48) * strideB + (long)t * strideT + kof;

  f32x4 acc0 = {0.f,0.f,0.f,0.f}, acc1 = {0.f,0.f,0.f,0.f};
  f32x4 acc2 = {0.f,0.f,0.f,0.f}, acc3 = {0.f,0.f,0.f,0.f};
  #pragma unroll
  for (int kk = 0; kk < 16; ++kk) {
    bf16x8 a  = *(const bf16x8*)(ap  + kk * 32);
    bf16x8 b0 = *(const bf16x8*)(bp0 + kk * 32);
    bf16x8 b1 = *(const bf16x8*)(bp1 + kk * 32);
    bf16x8 b2 = *(const bf16x8*)(bp2 + kk * 32);
    bf16x8 b3 = *(const bf16x8*)(bp3 + kk * 32);
    acc0 = __builtin_amdgcn_mfma_f32_16x16x32_bf16(a, b0, acc0, 0, 0, 0);
    acc1 = __builtin_amdgcn_mfma_f32_16x16x32_bf16(a, b1, acc1, 0, 0, 0);
    acc2 = __builtin_amdgcn_mfma_f32_16x16x32_bf16(a, b2, acc2, 0, 0, 0);
    acc3 = __builtin_amdgcn_mfma_f32_16x16x32_bf16(a, b3, acc3, 0, 0, 0);
  }
  const int m0 = (lane >> 4) * 4;
  #pragma unroll
  for (int r = 0; r < 4; ++r) {
    const int g = g0 + m0 + r;
    const float bv = bias[g];
    long base = ((long)t * G4 + g) * BATCH + n16;
    xg[base +  0] = f2bf(acc0[r] + bv);
    xg[base + 16] = f2bf(acc1[r] + bv);
    xg[base + 32] = f2bf(acc2[r] + bv);
    xg[base + 48] = f2bf(acc3[r] + bv);
  }
}

// Persistent recurrence. 256 WGs x 64 threads (1 wave each).
// Cross-WG h exchange goes through L3 via agent-scope (sc1) accesses ONLY —
// no __threadfence (which would invalidate/write back the whole per-XCD L2
// every step: that was 14.75us/step in R1).
__global__ __launch_bounds__(64) void rec_kernel(
    const unsigned short* __restrict__ Whb,   // [2048][512] bf16
    const unsigned short* __restrict__ xg,    // [T][2048][64] bf16
    unsigned short* __restrict__ hx,          // [2][64][512] bf16 (this layer)
    int* __restrict__ flags,                  // [4][64] (this layer)
    unsigned short* __restrict__ hseq,        // [T][64][512] bf16 or null
    float* __restrict__ out,                  // [64][512] or null
    int T) {
  __shared__ unsigned short whl[32 * 512];    // 32 KB, XOR-swizzled
  const int bid  = blockIdx.x;
  const int gq   = bid & 3;
  const int j    = bid >> 2;                  // 0..63
  const int lane = threadIdx.x;               // 0..63
  const int hidbase = j * 8;
  const int n16  = lane & 15;
  const int kof  = (lane >> 4) * 8;

  // ---- load Wh slice into LDS (swizzle byte col ^ ((r&7)<<4)) ----
  #pragma unroll 4
  for (int r = 0; r < 32; ++r) {
    const int gate = r >> 3;
    const long grow = (long)gate * HID + hidbase + (r & 7);
    bf16x8 v = *(const bf16x8*)(Whb + grow * HID + lane * 8);
    const int byteoff = r * 1024 + ((lane * 16) ^ ((r & 7) << 4));
    *(bf16x8*)((char*)whl + byteoff) = v;
  }
  __syncthreads();

  float c0 = 0.f, c1 = 0.f, c2 = 0.f, c3 = 0.f;  // cell state (lanes n16<8)
  const int* gflags = flags + gq * 64;
  const int bloc = (lane >> 4) * 4;

  for (int t = 0; t < T; ++t) {
    const int par = t & 1;
    if (t > 0) {
      int v;
      do {
        v = __hip_atomic_load(&gflags[lane], __ATOMIC_RELAXED, __HIP_MEMORY_SCOPE_AGENT);
      } while (__any(v < t));
      asm volatile("" ::: "memory");  // compile barrier: keep h loads below
    }

    // xg slice for this step (plain loads: written by a previous kernel)
    const int rr0 = n16, rr1 = 16 + n16;
    const int grow0 = (rr0 >> 3) * HID + hidbase + (rr0 & 7);
    const int grow1 = (rr1 >> 3) * HID + hidbase + (rr1 & 7);
    us4 xv0 = *(const us4*)(xg + ((long)t * G4 + grow0) * BATCH + gq * 16 + bloc);
    us4 xv1 = *(const us4*)(xg + ((long)t * G4 + grow1) * BATCH + gq * 16 + bloc);

    // ---- gates = h @ Wh^T ----  (h via 8B agent-scope loads: L1/L2-bypassing)
    const unsigned long long* hp64 = (const unsigned long long*)
        (hx + ((long)par * BATCH + gq * 16 + n16) * HID + kof);
    f32x4 acc0 = {0.f,0.f,0.f,0.f}, acc1 = {0.f,0.f,0.f,0.f};
    #pragma unroll
    for (int kk = 0; kk < 16; ++kk) {
      unsigned long long lo = __hip_atomic_load(hp64 + kk * 8,     __ATOMIC_RELAXED, __HIP_MEMORY_SCOPE_AGENT);
      unsigned long long hi = __hip_atomic_load(hp64 + kk * 8 + 1, __ATOMIC_RELAXED, __HIP_MEMORY_SCOPE_AGENT);
      union { unsigned long long q[2]; bf16x8 v; } u;
      u.q[0] = lo; u.q[1] = hi;
      const int colb = (kof + kk * 32) * 2;
      const int by0 = rr0 * 1024 + (colb ^ ((rr0 & 7) << 4));
      const int by1 = rr1 * 1024 + (colb ^ ((rr1 & 7) << 4));
      bf16x8 b0 = *(const bf16x8*)((const char*)whl + by0);
      bf16x8 b1 = *(const bf16x8*)((const char*)whl + by1);
      acc0 = __builtin_amdgcn_mfma_f32_16x16x32_bf16(u.v, b0, acc0, 0, 0, 0);
      acc1 = __builtin_amdgcn_mfma_f32_16x16x32_bf16(u.v, b1, acc1, 0, 0, 0);
    }
    #pragma unroll
    for (int r = 0; r < 4; ++r) {
      acc0[r] += bf2f(xv0[r]);
      acc1[r] += bf2f(xv1[r]);
    }

    // exchange with partner lane (n16 ^ 8): pairs (f,g) <-> (i,o)
    f32x4 o0, o1;
    #pragma unroll
    for (int r = 0; r < 4; ++r) {
      o0[r] = __shfl_xor(acc0[r], 8, 64);
      o1[r] = __shfl_xor(acc1[r], 8, 64);
    }

    if (n16 < 8) {
      const int hid = hidbase + n16;
      float cc[4] = {c0, c1, c2, c3};
      unsigned short* hw = hx + (long)(par ^ 1) * BATCH * HID;
      #pragma unroll
      for (int r = 0; r < 4; ++r) {
        const float fg = sigf(acc0[r]);      // f
        const float ig = sigf(o0[r]);        // i
        const float gg = tanh_fast(acc1[r]); // g
        const float og = sigf(o1[r]);        // o
        const float cn = fg * cc[r] + ig * gg;
        cc[r] = cn;
        const float h = og * tanh_fast(cn);
        const unsigned short hb = f2bf(h);
        const int brow = gq * 16 + bloc + r;
        // write-through (sc1) store: lands at L3, visible to peers' sc1 loads
        __hip_atomic_store(&hw[(long)brow * HID + hid], hb,
                           __ATOMIC_RELAXED, __HIP_MEMORY_SCOPE_AGENT);
        if (hseq) hseq[((long)t * BATCH + brow) * HID + hid] = hb;
        if (out && t == T - 1) out[(long)brow * HID + hid] = h;
      }
      c0 = cc[0]; c1 = cc[1]; c2 = cc[2]; c3 = cc[3];
    }

    // release: h sc1 stores ack'd at coherence point, then publish flag.
    asm volatile("s_waitcnt vmcnt(0)" ::: "memory");
    if (lane == 0)
      __hip_atomic_store(&flags[gq * 64 + j], t + 1,
                         __ATOMIC_RELAXED, __HIP_MEMORY_SCOPE_AGENT);
  }
}

extern "C" void kernel_launch(void* const* d_in, const int* in_sizes, int n_in,
                              void* d_out, int out_size, void* d_ws, size_t ws_size,
                              hipStream_t stream) {
  const float* x   = (const float*)d_in[0];
  const float* Wx0 = (const float*)d_in[1];
  const float* bx0 = (const float*)d_in[2];
  const float* Wh0 = (const float*)d_in[3];
  const float* bh0 = (const float*)d_in[4];
  const float* Wx1 = (const float*)d_in[5];
  const float* bx1 = (const float*)d_in[6];
  const float* Wh1 = (const float*)d_in[7];
  const float* bh1 = (const float*)d_in[8];

  char* ws = (char*)d_ws;
  size_t off = 0;
  auto alloc = [&](size_t bytes) -> char* {
    char* p = ws + off; off += (bytes + 255) & ~(size_t)255; return p;
  };
  unsigned short* xg   = (unsigned short*)alloc((size_t)T_STEPS * G4 * BATCH * 2);   // 128 MiB
  unsigned short* xb   = (unsigned short*)alloc((size_t)BATCH * T_STEPS * DIN * 2);  // 32 MiB
  unsigned short* hseq = (unsigned short*)alloc((size_t)T_STEPS * BATCH * HID * 2);  // 32 MiB
  unsigned short* Wx0b = (unsigned short*)alloc((size_t)G4 * DIN * 2);
  unsigned short* Wh0b = (unsigned short*)alloc((size_t)G4 * HID * 2);
  unsigned short* Wx1b = (unsigned short*)alloc((size_t)G4 * HID * 2);
  unsigned short* Wh1b = (unsigned short*)alloc((size_t)G4 * HID * 2);
  float* bs0 = (float*)alloc((size_t)G4 * 4);
  float* bs1 = (float*)alloc((size_t)G4 * 4);
  char* zbase = ws + off;  // everything below gets zeroed each call
  unsigned short* hx0 = (unsigned short*)alloc((size_t)2 * BATCH * HID * 2);
  unsigned short* hx1 = (unsigned short*)alloc((size_t)2 * BATCH * HID * 2);
  int* flags0 = (int*)alloc(4 * 64 * 4);
  int* flags1 = (int*)alloc(4 * 64 * 4);
  size_t zbytes = (size_t)((ws + off) - zbase);

  hipMemsetAsync(zbase, 0, zbytes, stream);

  // bf16 conversions + bias sums
  cvt_f32_bf16<<<1024, 256, 0, stream>>>(Wx0, Wx0b, (long)G4 * DIN);
  cvt_f32_bf16<<<1024, 256, 0, stream>>>(Wh0, Wh0b, (long)G4 * HID);
  cvt_f32_bf16<<<1024, 256, 0, stream>>>(Wx1, Wx1b, (long)G4 * HID);
  cvt_f32_bf16<<<1024, 256, 0, stream>>>(Wh1, Wh1b, (long)G4 * HID);
  cvt_f32_bf16<<<4096, 256, 0, stream>>>(x, xb, (long)BATCH * T_STEPS * DIN);
  bias_sum<<<8, 256, 0, stream>>>(bx0, bh0, bs0, G4);
  bias_sum<<<8, 256, 0, stream>>>(bx1, bh1, bs1, G4);

  dim3 pg(32, T_STEPS);
  // layer 0: IN = xb [B][T][D]  -> strideB = T*D, strideT = D
  proj_kernel<<<pg, 256, 0, stream>>>(xb, (long)T_STEPS * DIN, (long)DIN, Wx0b, bs0, xg);
  rec_kernel<<<256, 64, 0, stream>>>(Wh0b, xg, hx0, flags0, hseq, nullptr, T_STEPS);
  // layer 1: IN = hseq [T][B][H] -> strideB = H, strideT = B*H
  proj_kernel<<<pg, 256, 0, stream>>>(hseq, (long)HID, (long)BATCH * HID, Wx1b, bs1, xg);
  rec_kernel<<<256, 64, 0, stream>>>(Wh1b, xg, hx1, flags1, nullptr, (float*)d_out, T_STEPS);
}

// Round 3
// 6006.096 us; speedup vs baseline: 2.6967x; 1.1236x over previous
//
#include <hip/hip_runtime.h>
#include <hip/hip_bf16.h>
#include <stdint.h>

#define T_STEPS 512
#define BATCH   64
#define HID     512
#define DIN     512
#define G4      2048   // 4*HID

typedef __attribute__((ext_vector_type(8))) short bf16x8;
typedef __attribute__((ext_vector_type(4))) float f32x4;
typedef __attribute__((ext_vector_type(4))) unsigned short us4;

static __device__ __forceinline__ unsigned short f2bf(float f) {
  union { float f; unsigned u; } v; v.f = f;
  unsigned r = v.u + 0x7FFFu + ((v.u >> 16) & 1u);  // round-to-nearest-even
  return (unsigned short)(r >> 16);
}
static __device__ __forceinline__ float bf2f(unsigned short s) {
  union { unsigned u; float f; } v; v.u = ((unsigned)s) << 16;
  return v.f;
}
static __device__ __forceinline__ float sigf(float x) { return 1.f / (1.f + __expf(-x)); }
static __device__ __forceinline__ float tanh_fast(float x) {
  x = fminf(15.f, fmaxf(-15.f, x));
  float e = __expf(2.f * x);
  return (e - 1.f) / (e + 1.f);
}

__global__ void cvt_f32_bf16(const float* __restrict__ src, unsigned short* __restrict__ dst, long n) {
  long i = (long)blockIdx.x * blockDim.x + threadIdx.x;
  long st = (long)gridDim.x * blockDim.x;
  for (; i < n; i += st) dst[i] = f2bf(src[i]);
}

__global__ void bias_sum(const float* __restrict__ a, const float* __restrict__ b,
                         float* __restrict__ o, int n) {
  int i = blockIdx.x * blockDim.x + threadIdx.x;
  if (i < n) o[i] = a[i] + b[i];
}

// xg[t][g][b] = sum_k IN(b,t,k) * W[g][k] + bias[g]   (layer 0 only)
__global__ __launch_bounds__(256) void proj_kernel(
    const unsigned short* __restrict__ IN, long strideB, long strideT,
    const unsigned short* __restrict__ Wb, const float* __restrict__ bias,
    unsigned short* __restrict__ xg) {
  const int gtile = blockIdx.x;        // 0..31
  const int t     = blockIdx.y;        // 0..511
  const int wave  = threadIdx.x >> 6;  // 0..3
  const int lane  = threadIdx.x & 63;
  const int n16   = lane & 15;
  const int kof   = (lane >> 4) * 8;
  const int g0    = gtile * 64 + wave * 16;

  const unsigned short* ap  = Wb + (long)(g0 + n16) * DIN + kof;
  const unsigned short* bp0 = IN + (long)(n16 +  0) * strideB + (long)t * strideT + kof;
  const unsigned short* bp1 = IN + (long)(n16 + 16) * strideB + (long)t * strideT + kof;
  const unsigned short* bp2 = IN + (long)(n16 + 32) * strideB + (long)t * strideT + kof;
  const unsigned short* bp3 = IN + (long)(n16 + 48) * strideB + (long)t * strideT + kof;

  f32x4 acc0 = {0.f,0.f,0.f,0.f}, acc1 = {0.f,0.f,0.f,0.f};
  f32x4 acc2 = {0.f,0.f,0.f,0.f}, acc3 = {0.f,0.f,0.f,0.f};
  #pragma unroll
  for (int kk = 0; kk < 16; ++kk) {
    bf16x8 a  = *(const bf16x8*)(ap  + kk * 32);
    bf16x8 b0 = *(const bf16x8*)(bp0 + kk * 32);
    bf16x8 b1 = *(const bf16x8*)(bp1 + kk * 32);
    bf16x8 b2 = *(const bf16x8*)(bp2 + kk * 32);
    bf16x8 b3 = *(const bf16x8*)(bp3 + kk * 32);
    acc0 = __builtin_amdgcn_mfma_f32_16x16x32_bf16(a, b0, acc0, 0, 0, 0);
    acc1 = __builtin_amdgcn_mfma_f32_16x16x32_bf16(a, b1, acc1, 0, 0, 0);
    acc2 = __builtin_amdgcn_mfma_f32_16x16x32_bf16(a, b2, acc2, 0, 0, 0);
    acc3 = __builtin_amdgcn_mfma_f32_16x16x32_bf16(a, b3, acc3, 0, 0, 0);
  }
  const int m0 = (lane >> 4) * 4;
  #pragma unroll
  for (int r = 0; r < 4; ++r) {
    const int g = g0 + m0 + r;
    const float bv = bias[g];
    long base = ((long)t * G4 + g) * BATCH + n16;
    xg[base +  0] = f2bf(acc0[r] + bv);
    xg[base + 16] = f2bf(acc1[r] + bv);
    xg[base + 32] = f2bf(acc2[r] + bv);
    xg[base + 48] = f2bf(acc3[r] + bv);
  }
}

// Fused 2-layer pipelined recurrence. 256 WGs x 128 threads.
// wave0 = layer0 (Wh0 slice, 32KB LDS), wave1 = layer1 ([Wx1|Wh1] slice, 64KB).
// Layer1 lags layer0 by one step: critical depth 513, not 1024.
// LDS/WG = 98.8KB -> exactly 1 WG/CU -> all 256 co-resident (deadlock-safe).
// All cross-WG data (hseq, hx1, flags) moves via agent-scope (sc1/L3) ops only.
__global__ __launch_bounds__(128) void fused_rec(
    const unsigned short* __restrict__ Wh0b,  // [2048][512] bf16
    const unsigned short* __restrict__ xg0,   // [T][2048][64] bf16 (bias0 folded)
    const unsigned short* __restrict__ Wx1b,  // [2048][512] bf16
    const unsigned short* __restrict__ Wh1b,  // [2048][512] bf16
    const float* __restrict__ bs1,            // [2048] = bx1+bh1
    unsigned short* __restrict__ hseq,        // [T][64][512] bf16 (h1 ring)
    unsigned short* __restrict__ hx1,         // [2][64][512] bf16 (h2 dbuf)
    int* __restrict__ flags0,                 // [4][64]
    int* __restrict__ flags1,                 // [4][64]
    float* __restrict__ out,                  // [64][512]
    int T) {
  __shared__ unsigned short whl0[32 * 512];    // 32 KB
  __shared__ unsigned short whl1[32 * 1024];   // 64 KB
  __shared__ unsigned short hsc[2][128];       // 2 x 256 B repack scratch

  const int bid  = blockIdx.x;
  const int gq   = bid & 3;                    // batch group (16 batches)
  const int j    = bid >> 2;                   // 0..63, owns hid [j*8, j*8+8)
  const int wv   = threadIdx.x >> 6;
  const int lane = threadIdx.x & 63;
  const int hidbase = j * 8;
  const int n16  = lane & 15;
  const int q    = lane >> 4;
  const int kof  = q * 8;
  const int bloc = q * 4;
  const int rr0 = n16, rr1 = 16 + n16;
  const int grow0 = (rr0 >> 3) * HID + hidbase + (rr0 & 7);
  const int grow1 = (rr1 >> 3) * HID + hidbase + (rr1 & 7);

  // ---- LDS fill (each wave fills only its own region) ----
  if (wv == 0) {
    #pragma unroll 4
    for (int r = 0; r < 32; ++r) {
      const long grow = (long)(r >> 3) * HID + hidbase + (r & 7);
      bf16x8 v = *(const bf16x8*)(Wh0b + grow * HID + lane * 8);
      const int off = r * 1024 + ((lane * 16) ^ ((r & 7) << 4));
      *(bf16x8*)((char*)whl0 + off) = v;
    }
  } else {
    #pragma unroll 2
    for (int r = 0; r < 32; ++r) {
      const long grow = (long)(r >> 3) * HID + hidbase + (r & 7);
      bf16x8 va = *(const bf16x8*)(Wx1b + grow * HID + lane * 8);
      bf16x8 vb = *(const bf16x8*)(Wh1b + grow * HID + lane * 8);
      const int rb = r * 2048;
      *(bf16x8*)((char*)whl1 + rb + ((lane * 16) ^ ((r & 7) << 4))) = va;
      *(bf16x8*)((char*)whl1 + rb + ((1024 + lane * 16) ^ ((r & 7) << 4))) = vb;
    }
  }
  __syncthreads();  // once; afterwards the two waves are fully decoupled

  if (wv == 0) {
    // ================= layer 0 =================
    float c[4] = {0.f, 0.f, 0.f, 0.f};
    const int* f0g = flags0 + gq * 64;
    for (int t = 0; t < T; ++t) {
      // xg slice for this step: issue BEFORE the poll so the miss hides there
      us4 xv0 = *(const us4*)(xg0 + ((long)t * G4 + grow0) * BATCH + gq * 16 + bloc);
      us4 xv1 = *(const us4*)(xg0 + ((long)t * G4 + grow1) * BATCH + gq * 16 + bloc);

      f32x4 acc0 = {0.f,0.f,0.f,0.f}, acc1 = {0.f,0.f,0.f,0.f};
      if (t > 0) {
        int v;
        do {
          v = __hip_atomic_load(&f0g[lane], __ATOMIC_RELAXED, __HIP_MEMORY_SCOPE_AGENT);
        } while (__any(v < t));
        asm volatile("" ::: "memory");

        const unsigned long long* hp = (const unsigned long long*)
            (hseq + ((long)(t - 1) * BATCH + gq * 16 + n16) * HID + kof);
        #pragma unroll
        for (int kk = 0; kk < 16; ++kk) {
          unsigned long long lo = __hip_atomic_load(hp + kk * 8,     __ATOMIC_RELAXED, __HIP_MEMORY_SCOPE_AGENT);
          unsigned long long hi = __hip_atomic_load(hp + kk * 8 + 1, __ATOMIC_RELAXED, __HIP_MEMORY_SCOPE_AGENT);
          union { unsigned long long qq[2]; bf16x8 v; } u; u.qq[0] = lo; u.qq[1] = hi;
          const int colb = (kof + kk * 32) * 2;
          bf16x8 b0 = *(const bf16x8*)((const char*)whl0 + rr0 * 1024 + (colb ^ ((rr0 & 7) << 4)));
          bf16x8 b1 = *(const bf16x8*)((const char*)whl0 + rr1 * 1024 + (colb ^ ((rr1 & 7) << 4)));
          acc0 = __builtin_amdgcn_mfma_f32_16x16x32_bf16(u.v, b0, acc0, 0, 0, 0);
          acc1 = __builtin_amdgcn_mfma_f32_16x16x32_bf16(u.v, b1, acc1, 0, 0, 0);
        }
      }
      #pragma unroll
      for (int r = 0; r < 4; ++r) { acc0[r] += bf2f(xv0[r]); acc1[r] += bf2f(xv1[r]); }

      f32x4 o0, o1;
      #pragma unroll
      for (int r = 0; r < 4; ++r) {
        o0[r] = __shfl_xor(acc0[r], 8, 64);
        o1[r] = __shfl_xor(acc1[r], 8, 64);
      }
      if (n16 < 8) {
        #pragma unroll
        for (int r = 0; r < 4; ++r) {
          const float fg = sigf(acc0[r]);
          const float ig = sigf(o0[r]);
          const float gg = tanh_fast(acc1[r]);
          const float og = sigf(o1[r]);
          const float cn = fg * c[r] + ig * gg;
          c[r] = cn;
          const float h = og * tanh_fast(cn);
          *(unsigned short*)((char*)hsc[0] + (bloc + r) * 16 + n16 * 2) = f2bf(h);
        }
      }
      asm volatile("s_waitcnt lgkmcnt(0)" ::: "memory");
      if (lane < 32) {  // 32 coalesced 8B sc1 stores (vs 128 x 2B)
        unsigned long long v8 = *(const unsigned long long*)((const char*)hsc[0] + lane * 8);
        unsigned long long* dst = (unsigned long long*)
            (hseq + ((long)t * BATCH + gq * 16 + (lane >> 1)) * HID + hidbase + (lane & 1) * 4);
        __hip_atomic_store(dst, v8, __ATOMIC_RELAXED, __HIP_MEMORY_SCOPE_AGENT);
      }
      asm volatile("s_waitcnt vmcnt(0)" ::: "memory");  // h at coherence point
      if (lane == 0)
        __hip_atomic_store(&flags0[gq * 64 + j], t + 1, __ATOMIC_RELAXED, __HIP_MEMORY_SCOPE_AGENT);
    }
  } else {
    // ================= layer 1 =================
    float c[4] = {0.f, 0.f, 0.f, 0.f};
    const int* f0g = flags0 + gq * 64;
    const int* f1g = flags1 + gq * 64;
    const float b0v = bs1[grow0], b1v = bs1[grow1];
    for (int t = 0; t < T; ++t) {
      int v0, v1;
      do {
        v0 = __hip_atomic_load(&f0g[lane], __ATOMIC_RELAXED, __HIP_MEMORY_SCOPE_AGENT);
        v1 = __hip_atomic_load(&f1g[lane], __ATOMIC_RELAXED, __HIP_MEMORY_SCOPE_AGENT);
      } while (__any((v0 < t + 1) || (v1 < t)));
      asm volatile("" ::: "memory");

      f32x4 acc0 = {0.f,0.f,0.f,0.f}, acc1 = {0.f,0.f,0.f,0.f};
      // K part 1: Wx1 * h1[t]
      const unsigned long long* hpa = (const unsigned long long*)
          (hseq + ((long)t * BATCH + gq * 16 + n16) * HID + kof);
      #pragma unroll
      for (int kk = 0; kk < 16; ++kk) {
        unsigned long long lo = __hip_atomic_load(hpa + kk * 8,     __ATOMIC_RELAXED, __HIP_MEMORY_SCOPE_AGENT);
        unsigned long long hi = __hip_atomic_load(hpa + kk * 8 + 1, __ATOMIC_RELAXED, __HIP_MEMORY_SCOPE_AGENT);
        union { unsigned long long qq[2]; bf16x8 v; } u; u.qq[0] = lo; u.qq[1] = hi;
        const int colb = (kof + kk * 32) * 2;
        bf16x8 b0 = *(const bf16x8*)((const char*)whl1 + rr0 * 2048 + (colb ^ ((rr0 & 7) << 4)));
        bf16x8 b1 = *(const bf16x8*)((const char*)whl1 + rr1 * 2048 + (colb ^ ((rr1 & 7) << 4)));
        acc0 = __builtin_amdgcn_mfma_f32_16x16x32_bf16(u.v, b0, acc0, 0, 0, 0);
        acc1 = __builtin_amdgcn_mfma_f32_16x16x32_bf16(u.v, b1, acc1, 0, 0, 0);
      }
      // K part 2: Wh1 * h2[t-1]
      if (t > 0) {
        const int par = t & 1;
        const unsigned long long* hpb = (const unsigned long long*)
            (hx1 + ((long)par * BATCH + gq * 16 + n16) * HID + kof);
        #pragma unroll
        for (int kk = 0; kk < 16; ++kk) {
          unsigned long long lo = __hip_atomic_load(hpb + kk * 8,     __ATOMIC_RELAXED, __HIP_MEMORY_SCOPE_AGENT);
          unsigned long long hi = __hip_atomic_load(hpb + kk * 8 + 1, __ATOMIC_RELAXED, __HIP_MEMORY_SCOPE_AGENT);
          union { unsigned long long qq[2]; bf16x8 v; } u; u.qq[0] = lo; u.qq[1] = hi;
          const int colb = 1024 + (kof + kk * 32) * 2;
          bf16x8 b0 = *(const bf16x8*)((const char*)whl1 + rr0 * 2048 + (colb ^ ((rr0 & 7) << 4)));
          bf16x8 b1 = *(const bf16x8*)((const char*)whl1 + rr1 * 2048 + (colb ^ ((rr1 & 7) << 4)));
          acc0 = __builtin_amdgcn_mfma_f32_16x16x32_bf16(u.v, b0, acc0, 0, 0, 0);
          acc1 = __builtin_amdgcn_mfma_f32_16x16x32_bf16(u.v, b1, acc1, 0, 0, 0);
        }
      }
      #pragma unroll
      for (int r = 0; r < 4; ++r) { acc0[r] += b0v; acc1[r] += b1v; }

      f32x4 o0, o1;
      #pragma unroll
      for (int r = 0; r < 4; ++r) {
        o0[r] = __shfl_xor(acc0[r], 8, 64);
        o1[r] = __shfl_xor(acc1[r], 8, 64);
      }
      if (n16 < 8) {
        const int hid = hidbase + n16;
        #pragma unroll
        for (int r = 0; r < 4; ++r) {
          const float fg = sigf(acc0[r]);
          const float ig = sigf(o0[r]);
          const float gg = tanh_fast(acc1[r]);
          const float og = sigf(o1[r]);
          const float cn = fg * c[r] + ig * gg;
          c[r] = cn;
          const float h = og * tanh_fast(cn);
          *(unsigned short*)((char*)hsc[1] + (bloc + r) * 16 + n16 * 2) = f2bf(h);
          if (t == T - 1) out[(long)(gq * 16 + bloc + r) * HID + hid] = h;
        }
      }
      asm volatile("s_waitcnt lgkmcnt(0)" ::: "memory");
      if (lane < 32) {
        unsigned long long v8 = *(const unsigned long long*)((const char*)hsc[1] + lane * 8);
        unsigned long long* dst = (unsigned long long*)
            (hx1 + ((long)((t & 1) ^ 1) * BATCH + gq * 16 + (lane >> 1)) * HID + hidbase + (lane & 1) * 4);
        __hip_atomic_store(dst, v8, __ATOMIC_RELAXED, __HIP_MEMORY_SCOPE_AGENT);
      }
      asm volatile("s_waitcnt vmcnt(0)" ::: "memory");
      if (lane == 0)
        __hip_atomic_store(&flags1[gq * 64 + j], t + 1, __ATOMIC_RELAXED, __HIP_MEMORY_SCOPE_AGENT);
    }
  }
}

extern "C" void kernel_launch(void* const* d_in, const int* in_sizes, int n_in,
                              void* d_out, int out_size, void* d_ws, size_t ws_size,
                              hipStream_t stream) {
  const float* x   = (const float*)d_in[0];
  const float* Wx0 = (const float*)d_in[1];
  const float* bx0 = (const float*)d_in[2];
  const float* Wh0 = (const float*)d_in[3];
  const float* bh0 = (const float*)d_in[4];
  const float* Wx1 = (const float*)d_in[5];
  const float* bx1 = (const float*)d_in[6];
  const float* Wh1 = (const float*)d_in[7];
  const float* bh1 = (const float*)d_in[8];

  char* ws = (char*)d_ws;
  size_t off = 0;
  auto alloc = [&](size_t bytes) -> char* {
    char* p = ws + off; off += (bytes + 255) & ~(size_t)255; return p;
  };
  unsigned short* xg   = (unsigned short*)alloc((size_t)T_STEPS * G4 * BATCH * 2);   // 128 MiB
  unsigned short* xb   = (unsigned short*)alloc((size_t)BATCH * T_STEPS * DIN * 2);  // 32 MiB
  unsigned short* hseq = (unsigned short*)alloc((size_t)T_STEPS * BATCH * HID * 2);  // 32 MiB
  unsigned short* Wx0b = (unsigned short*)alloc((size_t)G4 * DIN * 2);
  unsigned short* Wh0b = (unsigned short*)alloc((size_t)G4 * HID * 2);
  unsigned short* Wx1b = (unsigned short*)alloc((size_t)G4 * HID * 2);
  unsigned short* Wh1b = (unsigned short*)alloc((size_t)G4 * HID * 2);
  float* bs0 = (float*)alloc((size_t)G4 * 4);
  float* bs1 = (float*)alloc((size_t)G4 * 4);
  char* zbase = ws + off;  // zeroed each call
  unsigned short* hx1 = (unsigned short*)alloc((size_t)2 * BATCH * HID * 2);
  int* flags0 = (int*)alloc(4 * 64 * 4);
  int* flags1 = (int*)alloc(4 * 64 * 4);
  size_t zbytes = (size_t)((ws + off) - zbase);

  hipMemsetAsync(zbase, 0, zbytes, stream);

  cvt_f32_bf16<<<1024, 256, 0, stream>>>(Wx0, Wx0b, (long)G4 * DIN);
  cvt_f32_bf16<<<1024, 256, 0, stream>>>(Wh0, Wh0b, (long)G4 * HID);
  cvt_f32_bf16<<<1024, 256, 0, stream>>>(Wx1, Wx1b, (long)G4 * HID);
  cvt_f32_bf16<<<1024, 256, 0, stream>>>(Wh1, Wh1b, (long)G4 * HID);
  cvt_f32_bf16<<<4096, 256, 0, stream>>>(x, xb, (long)BATCH * T_STEPS * DIN);
  bias_sum<<<8, 256, 0, stream>>>(bx0, bh0, bs0, G4);
  bias_sum<<<8, 256, 0, stream>>>(bx1, bh1, bs1, G4);

  dim3 pg(32, T_STEPS);
  // layer 0 input projections: IN = xb [B][T][D] -> strideB = T*D, strideT = D
  proj_kernel<<<pg, 256, 0, stream>>>(xb, (long)T_STEPS * DIN, (long)DIN, Wx0b, bs0, xg);
  // fused pipelined 2-layer recurrence
  fused_rec<<<256, 128, 0, stream>>>(Wh0b, xg, Wx1b, Wh1b, bs1,
                                     hseq, hx1, flags0, flags1,
                                     (float*)d_out, T_STEPS);
}

// Round 5
// 4446.605 us; speedup vs baseline: 3.6425x; 1.3507x over previous
//
#include <hip/hip_runtime.h>
#include <hip/hip_bf16.h>
#include <stdint.h>

#define T_STEPS 512
#define BATCH   64
#define HID     512
#define DIN     512
#define G4      2048   // 4*HID
// blocked h layout: [t or par][j=64][gq=4][b=16][h=8] ushorts; per-t stride:
#define HBLK_T  32768  // 64*4*16*8

typedef __attribute__((ext_vector_type(8))) short bf16x8;
typedef __attribute__((ext_vector_type(4))) float f32x4;
typedef __attribute__((ext_vector_type(4))) unsigned short us4;

static __device__ __forceinline__ unsigned short f2bf(float f) {
  union { float f; unsigned u; } v; v.f = f;
  unsigned r = v.u + 0x7FFFu + ((v.u >> 16) & 1u);  // round-to-nearest-even
  return (unsigned short)(r >> 16);
}
static __device__ __forceinline__ float bf2f(unsigned short s) {
  union { unsigned u; float f; } v; v.u = ((unsigned)s) << 16;
  return v.f;
}
static __device__ __forceinline__ float sigf(float x) { return 1.f / (1.f + __expf(-x)); }
static __device__ __forceinline__ float tanh_fast(float x) {
  x = fminf(15.f, fmaxf(-15.f, x));
  float e = __expf(2.f * x);
  return (e - 1.f) / (e + 1.f);
}

__global__ void cvt_f32_bf16(const float* __restrict__ src, unsigned short* __restrict__ dst, long n) {
  long i = (long)blockIdx.x * blockDim.x + threadIdx.x;
  long st = (long)gridDim.x * blockDim.x;
  for (; i < n; i += st) dst[i] = f2bf(src[i]);
}

__global__ void bias_sum(const float* __restrict__ a, const float* __restrict__ b,
                         float* __restrict__ o, int n) {
  int i = blockIdx.x * blockDim.x + threadIdx.x;
  if (i < n) o[i] = a[i] + b[i];
}

// xg[t][g][b] = sum_k IN(b,t,k) * W[g][k] + bias[g]   (layer 0 only)
__global__ __launch_bounds__(256) void proj_kernel(
    const unsigned short* __restrict__ IN, long strideB, long strideT,
    const unsigned short* __restrict__ Wb, const float* __restrict__ bias,
    unsigned short* __restrict__ xg) {
  const int gtile = blockIdx.x;        // 0..31
  const int t     = blockIdx.y;        // 0..511
  const int wave  = threadIdx.x >> 6;  // 0..3
  const int lane  = threadIdx.x & 63;
  const int n16   = lane & 15;
  const int kof   = (lane >> 4) * 8;
  const int g0    = gtile * 64 + wave * 16;

  const unsigned short* ap  = Wb + (long)(g0 + n16) * DIN + kof;
  const unsigned short* bp0 = IN + (long)(n16 +  0) * strideB + (long)t * strideT + kof;
  const unsigned short* bp1 = IN + (long)(n16 + 16) * strideB + (long)t * strideT + kof;
  const unsigned short* bp2 = IN + (long)(n16 + 32) * strideB + (long)t * strideT + kof;
  const unsigned short* bp3 = IN + (long)(n16 + 48) * strideB + (long)t * strideT + kof;

  f32x4 acc0 = {0.f,0.f,0.f,0.f}, acc1 = {0.f,0.f,0.f,0.f};
  f32x4 acc2 = {0.f,0.f,0.f,0.f}, acc3 = {0.f,0.f,0.f,0.f};
  #pragma unroll
  for (int kk = 0; kk < 16; ++kk) {
    bf16x8 a  = *(const bf16x8*)(ap  + kk * 32);
    bf16x8 b0 = *(const bf16x8*)(bp0 + kk * 32);
    bf16x8 b1 = *(const bf16x8*)(bp1 + kk * 32);
    bf16x8 b2 = *(const bf16x8*)(bp2 + kk * 32);
    bf16x8 b3 = *(const bf16x8*)(bp3 + kk * 32);
    acc0 = __builtin_amdgcn_mfma_f32_16x16x32_bf16(a, b0, acc0, 0, 0, 0);
    acc1 = __builtin_amdgcn_mfma_f32_16x16x32_bf16(a, b1, acc1, 0, 0, 0);
    acc2 = __builtin_amdgcn_mfma_f32_16x16x32_bf16(a, b2, acc2, 0, 0, 0);
    acc3 = __builtin_amdgcn_mfma_f32_16x16x32_bf16(a, b3, acc3, 0, 0, 0);
  }
  const int m0 = (lane >> 4) * 4;
  #pragma unroll
  for (int r = 0; r < 4; ++r) {
    const int g = g0 + m0 + r;
    const float bv = bias[g];
    long base = ((long)t * G4 + g) * BATCH + n16;
    xg[base +  0] = f2bf(acc0[r] + bv);
    xg[base + 16] = f2bf(acc1[r] + bv);
    xg[base + 32] = f2bf(acc2[r] + bv);
    xg[base + 48] = f2bf(acc3[r] + bv);
  }
}

// Fused 2-layer pipelined recurrence. 256 WGs x 128 threads.
// wave0 = layer0, wave1 = layer1 (lag-1 pipeline). All cross-WG h data moves
// via agent-scope sc1 ops through L3, in BLOCKED layout so each WG's per-step
// publication is 4 full 64B lines (no partial-line RMW on the release path).
__global__ __launch_bounds__(128) void fused_rec(
    const unsigned short* __restrict__ Wh0b,  // [2048][512] bf16
    const unsigned short* __restrict__ xg0,   // [T][2048][64] bf16 (bias0 folded)
    const unsigned short* __restrict__ Wx1b,  // [2048][512] bf16
    const unsigned short* __restrict__ Wh1b,  // [2048][512] bf16
    const float* __restrict__ bs1,            // [2048] = bx1+bh1
    unsigned short* __restrict__ hseq,        // [T][64][4][16][8] bf16 (h1 ring)
    unsigned short* __restrict__ hx1,         // [2][64][4][16][8] bf16 (h2 dbuf)
    int* __restrict__ flags0,                 // [4][64]
    int* __restrict__ flags1,                 // [4][64]
    float* __restrict__ out,                  // [64][512]
    int T) {
  __shared__ unsigned short whl0[32 * 512];    // 32 KB
  __shared__ unsigned short whl1[32 * 1024];   // 64 KB
  __shared__ unsigned short hsc[2][128];       // 2 x 256 B repack scratch

  const int bid  = blockIdx.x;
  const int gq   = bid & 3;                    // batch group (16 batches)
  const int j    = bid >> 2;                   // 0..63, owns hid [j*8, j*8+8)
  const int wv   = threadIdx.x >> 6;
  const int lane = threadIdx.x & 63;
  const int hidbase = j * 8;
  const int n16  = lane & 15;
  const int q    = lane >> 4;
  const int kof  = q * 8;
  const int bloc = q * 4;
  const int rr0 = n16, rr1 = 16 + n16;
  const int grow0 = (rr0 >> 3) * HID + hidbase + (rr0 & 7);
  const int grow1 = (rr1 >> 3) * HID + hidbase + (rr1 & 7);
  // blocked-layout read offset for lane (n16,q) at K-step kk:
  //   hid k = kk*32 + q*8 + e  ->  owner j' = kk*4+q (stride 512 ushorts =
  //   128 ulls), block offset = gq*128 + n16*8 + e ushorts.
  const int rdbase = gq * 128 + n16 * 8;       // ushort units
  const int myblk  = (j * 4 + gq) * 128;       // this WG's write block (ushorts)

  // ---- LDS fill ----
  if (wv == 0) {
    #pragma unroll 4
    for (int r = 0; r < 32; ++r) {
      const long grow = (long)(r >> 3) * HID + hidbase + (r & 7);
      bf16x8 v = *(const bf16x8*)(Wh0b + grow * HID + lane * 8);
      const int off = r * 1024 + ((lane * 16) ^ ((r & 7) << 4));
      *(bf16x8*)((char*)whl0 + off) = v;
    }
  } else {
    #pragma unroll 2
    for (int r = 0; r < 32; ++r) {
      const long grow = (long)(r >> 3) * HID + hidbase + (r & 7);
      bf16x8 va = *(const bf16x8*)(Wx1b + grow * HID + lane * 8);
      bf16x8 vb = *(const bf16x8*)(Wh1b + grow * HID + lane * 8);
      const int rb = r * 2048;
      *(bf16x8*)((char*)whl1 + rb + ((lane * 16) ^ ((r & 7) << 4))) = va;
      *(bf16x8*)((char*)whl1 + rb + ((1024 + lane * 16) ^ ((r & 7) << 4))) = vb;
    }
  }
  __syncthreads();  // once; afterwards the two waves are fully decoupled

  if (wv == 0) {
    // ================= layer 0 =================
    float c[4] = {0.f, 0.f, 0.f, 0.f};
    const int* f0g = flags0 + gq * 64;
    for (int t = 0; t < T; ++t) {
      // xg slice: issue BEFORE the poll so the HBM miss hides under the wait
      us4 xv0 = *(const us4*)(xg0 + ((long)t * G4 + grow0) * BATCH + gq * 16 + bloc);
      us4 xv1 = *(const us4*)(xg0 + ((long)t * G4 + grow1) * BATCH + gq * 16 + bloc);

      f32x4 acc0 = {0.f,0.f,0.f,0.f}, acc1 = {0.f,0.f,0.f,0.f};
      if (t > 0) {
        int v;
        do {
          v = __hip_atomic_load(&f0g[lane], __ATOMIC_RELAXED, __HIP_MEMORY_SCOPE_AGENT);
        } while (__any(v < t));
        asm volatile("" ::: "memory");

        const unsigned long long* hp = (const unsigned long long*)
            (hseq + (long)(t - 1) * HBLK_T + rdbase);
        #pragma unroll
        for (int kk = 0; kk < 16; ++kk) {
          const int boff = (kk * 4 + q) * 128;  // j' stride = 512 ushorts = 128 ulls
          unsigned long long lo = __hip_atomic_load(hp + boff,     __ATOMIC_RELAXED, __HIP_MEMORY_SCOPE_AGENT);
          unsigned long long hi = __hip_atomic_load(hp + boff + 1, __ATOMIC_RELAXED, __HIP_MEMORY_SCOPE_AGENT);
          union { unsigned long long qq[2]; bf16x8 v; } u; u.qq[0] = lo; u.qq[1] = hi;
          const int colb = (kof + kk * 32) * 2;
          bf16x8 b0 = *(const bf16x8*)((const char*)whl0 + rr0 * 1024 + (colb ^ ((rr0 & 7) << 4)));
          bf16x8 b1 = *(const bf16x8*)((const char*)whl0 + rr1 * 1024 + (colb ^ ((rr1 & 7) << 4)));
          acc0 = __builtin_amdgcn_mfma_f32_16x16x32_bf16(u.v, b0, acc0, 0, 0, 0);
          acc1 = __builtin_amdgcn_mfma_f32_16x16x32_bf16(u.v, b1, acc1, 0, 0, 0);
        }
      }
      #pragma unroll
      for (int r = 0; r < 4; ++r) { acc0[r] += bf2f(xv0[r]); acc1[r] += bf2f(xv1[r]); }

      f32x4 o0, o1;
      #pragma unroll
      for (int r = 0; r < 4; ++r) {
        o0[r] = __shfl_xor(acc0[r], 8, 64);
        o1[r] = __shfl_xor(acc1[r], 8, 64);
      }
      if (n16 < 8) {
        #pragma unroll
        for (int r = 0; r < 4; ++r) {
          const float fg = sigf(acc0[r]);
          const float ig = sigf(o0[r]);
          const float gg = tanh_fast(acc1[r]);
          const float og = sigf(o1[r]);
          const float cn = fg * c[r] + ig * gg;
          c[r] = cn;
          const float h = og * tanh_fast(cn);
          *(unsigned short*)((char*)hsc[0] + (bloc + r) * 16 + n16 * 2) = f2bf(h);
        }
      }
      asm volatile("s_waitcnt lgkmcnt(0)" ::: "memory");
      if (lane < 32) {  // 32 x 8B = 4 FULL 64B lines, contiguous
        unsigned long long v8 = *(const unsigned long long*)((const char*)hsc[0] + lane * 8);
        unsigned long long* dst = (unsigned long long*)
            (hseq + (long)t * HBLK_T + myblk) + lane;
        __hip_atomic_store(dst, v8, __ATOMIC_RELAXED, __HIP_MEMORY_SCOPE_AGENT);
      }
      asm volatile("s_waitcnt vmcnt(0)" ::: "memory");  // h at coherence point
      if (lane == 0)
        __hip_atomic_store(&flags0[gq * 64 + j], t + 1, __ATOMIC_RELAXED, __HIP_MEMORY_SCOPE_AGENT);
    }
  } else {
    // ================= layer 1 =================
    float c[4] = {0.f, 0.f, 0.f, 0.f};
    const int* f0g = flags0 + gq * 64;
    const int* f1g = flags1 + gq * 64;
    const float b0v = bs1[grow0], b1v = bs1[grow1];
    for (int t = 0; t < T; ++t) {
      // ---- off-chain half: needs only flags0 (L0 runs ahead) ----
      {
        int v0;
        do {
          v0 = __hip_atomic_load(&f0g[lane], __ATOMIC_RELAXED, __HIP_MEMORY_SCOPE_AGENT);
        } while (__any(v0 < t + 1));
        asm volatile("" ::: "memory");
      }
      f32x4 acc0 = {0.f,0.f,0.f,0.f}, acc1 = {0.f,0.f,0.f,0.f};
      const unsigned long long* hpa = (const unsigned long long*)
          (hseq + (long)t * HBLK_T + rdbase);
      #pragma unroll
      for (int kk = 0; kk < 16; ++kk) {
        const int boff = (kk * 4 + q) * 128;
        unsigned long long lo = __hip_atomic_load(hpa + boff,     __ATOMIC_RELAXED, __HIP_MEMORY_SCOPE_AGENT);
        unsigned long long hi = __hip_atomic_load(hpa + boff + 1, __ATOMIC_RELAXED, __HIP_MEMORY_SCOPE_AGENT);
        union { unsigned long long qq[2]; bf16x8 v; } u; u.qq[0] = lo; u.qq[1] = hi;
        const int colb = (kof + kk * 32) * 2;
        bf16x8 b0 = *(const bf16x8*)((const char*)whl1 + rr0 * 2048 + (colb ^ ((rr0 & 7) << 4)));
        bf16x8 b1 = *(const bf16x8*)((const char*)whl1 + rr1 * 2048 + (colb ^ ((rr1 & 7) << 4)));
        acc0 = __builtin_amdgcn_mfma_f32_16x16x32_bf16(u.v, b0, acc0, 0, 0, 0);
        acc1 = __builtin_amdgcn_mfma_f32_16x16x32_bf16(u.v, b1, acc1, 0, 0, 0);
      }
      // ---- recurrent half: needs flags1 (peers' h2[t-1]) ----
      if (t > 0) {
        int v1;
        do {
          v1 = __hip_atomic_load(&f1g[lane], __ATOMIC_RELAXED, __HIP_MEMORY_SCOPE_AGENT);
        } while (__any(v1 < t));
        asm volatile("" ::: "memory");
        const int par = t & 1;
        const unsigned long long* hpb = (const unsigned long long*)
            (hx1 + (long)par * HBLK_T + rdbase);
        #pragma unroll
        for (int kk = 0; kk < 16; ++kk) {
          const int boff = (kk * 4 + q) * 128;
          unsigned long long lo = __hip_atomic_load(hpb + boff,     __ATOMIC_RELAXED, __HIP_MEMORY_SCOPE_AGENT);
          unsigned long long hi = __hip_atomic_load(hpb + boff + 1, __ATOMIC_RELAXED, __HIP_MEMORY_SCOPE_AGENT);
          union { unsigned long long qq[2]; bf16x8 v; } u; u.qq[0] = lo; u.qq[1] = hi;
          const int colb = 1024 + (kof + kk * 32) * 2;
          bf16x8 b0 = *(const bf16x8*)((const char*)whl1 + rr0 * 2048 + (colb ^ ((rr0 & 7) << 4)));
          bf16x8 b1 = *(const bf16x8*)((const char*)whl1 + rr1 * 2048 + (colb ^ ((rr1 & 7) << 4)));
          acc0 = __builtin_amdgcn_mfma_f32_16x16x32_bf16(u.v, b0, acc0, 0, 0, 0);
          acc1 = __builtin_amdgcn_mfma_f32_16x16x32_bf16(u.v, b1, acc1, 0, 0, 0);
        }
      }
      #pragma unroll
      for (int r = 0; r < 4; ++r) { acc0[r] += b0v; acc1[r] += b1v; }

      f32x4 o0, o1;
      #pragma unroll
      for (int r = 0; r < 4; ++r) {
        o0[r] = __shfl_xor(acc0[r], 8, 64);
        o1[r] = __shfl_xor(acc1[r], 8, 64);
      }
      if (n16 < 8) {
        const int hid = hidbase + n16;
        #pragma unroll
        for (int r = 0; r < 4; ++r) {
          const float fg = sigf(acc0[r]);
          const float ig = sigf(o0[r]);
          const float gg = tanh_fast(acc1[r]);
          const float og = sigf(o1[r]);
          const float cn = fg * c[r] + ig * gg;
          c[r] = cn;
          const float h = og * tanh_fast(cn);
          *(unsigned short*)((char*)hsc[1] + (bloc + r) * 16 + n16 * 2) = f2bf(h);
          if (t == T - 1) out[(long)(gq * 16 + bloc + r) * HID + hid] = h;
        }
      }
      asm volatile("s_waitcnt lgkmcnt(0)" ::: "memory");
      if (lane < 32) {
        unsigned long long v8 = *(const unsigned long long*)((const char*)hsc[1] + lane * 8);
        unsigned long long* dst = (unsigned long long*)
            (hx1 + (long)((t & 1) ^ 1) * HBLK_T + myblk) + lane;
        __hip_atomic_store(dst, v8, __ATOMIC_RELAXED, __HIP_MEMORY_SCOPE_AGENT);
      }
      asm volatile("s_waitcnt vmcnt(0)" ::: "memory");
      if (lane == 0)
        __hip_atomic_store(&flags1[gq * 64 + j], t + 1, __ATOMIC_RELAXED, __HIP_MEMORY_SCOPE_AGENT);
    }
  }
}

extern "C" void kernel_launch(void* const* d_in, const int* in_sizes, int n_in,
                              void* d_out, int out_size, void* d_ws, size_t ws_size,
                              hipStream_t stream) {
  const float* x   = (const float*)d_in[0];
  const float* Wx0 = (const float*)d_in[1];
  const float* bx0 = (const float*)d_in[2];
  const float* Wh0 = (const float*)d_in[3];
  const float* bh0 = (const float*)d_in[4];
  const float* Wx1 = (const float*)d_in[5];
  const float* bx1 = (const float*)d_in[6];
  const float* Wh1 = (const float*)d_in[7];
  const float* bh1 = (const float*)d_in[8];

  char* ws = (char*)d_ws;
  size_t off = 0;
  auto alloc = [&](size_t bytes) -> char* {
    char* p = ws + off; off += (bytes + 255) & ~(size_t)255; return p;
  };
  unsigned short* xg   = (unsigned short*)alloc((size_t)T_STEPS * G4 * BATCH * 2);   // 128 MiB
  unsigned short* xb   = (unsigned short*)alloc((size_t)BATCH * T_STEPS * DIN * 2);  // 32 MiB
  unsigned short* hseq = (unsigned short*)alloc((size_t)T_STEPS * HBLK_T * 2);       // 32 MiB
  unsigned short* Wx0b = (unsigned short*)alloc((size_t)G4 * DIN * 2);
  unsigned short* Wh0b = (unsigned short*)alloc((size_t)G4 * HID * 2);
  unsigned short* Wx1b = (unsigned short*)alloc((size_t)G4 * HID * 2);
  unsigned short* Wh1b = (unsigned short*)alloc((size_t)G4 * HID * 2);
  float* bs0 = (float*)alloc((size_t)G4 * 4);
  float* bs1 = (float*)alloc((size_t)G4 * 4);
  char* zbase = ws + off;  // zeroed each call
  unsigned short* hx1 = (unsigned short*)alloc((size_t)2 * HBLK_T * 2);
  int* flags0 = (int*)alloc(4 * 64 * 4);
  int* flags1 = (int*)alloc(4 * 64 * 4);
  size_t zbytes = (size_t)((ws + off) - zbase);

  hipMemsetAsync(zbase, 0, zbytes, stream);

  cvt_f32_bf16<<<1024, 256, 0, stream>>>(Wx0, Wx0b, (long)G4 * DIN);
  cvt_f32_bf16<<<1024, 256, 0, stream>>>(Wh0, Wh0b, (long)G4 * HID);
  cvt_f32_bf16<<<1024, 256, 0, stream>>>(Wx1, Wx1b, (long)G4 * HID);
  cvt_f32_bf16<<<1024, 256, 0, stream>>>(Wh1, Wh1b, (long)G4 * HID);
  cvt_f32_bf16<<<4096, 256, 0, stream>>>(x, xb, (long)BATCH * T_STEPS * DIN);
  bias_sum<<<8, 256, 0, stream>>>(bx0, bh0, bs0, G4);
  bias_sum<<<8, 256, 0, stream>>>(bx1, bh1, bs1, G4);

  dim3 pg(32, T_STEPS);
  // layer 0 input projections: IN = xb [B][T][D] -> strideB = T*D, strideT = D
  proj_kernel<<<pg, 256, 0, stream>>>(xb, (long)T_STEPS * DIN, (long)DIN, Wx0b, bs0, xg);
  // fused pipelined 2-layer recurrence
  fused_rec<<<256, 128, 0, stream>>>(Wh0b, xg, Wx1b, Wh1b, bs1,
                                     hseq, hx1, flags0, flags1,
                                     (float*)d_out, T_STEPS);
}

// Round 6
// 2042.830 us; speedup vs baseline: 7.9285x; 2.1767x over previous
//
#include <hip/hip_runtime.h>
#include <hip/hip_bf16.h>
#include <stdint.h>

#define T_STEPS 512
#define BATCH   64
#define HID     512
#define DIN     512
#define G4      2048   // 4*HID
// blocked h layout: [t][j=64][gq=4][b=16][h=8] ushorts; per-t stride:
#define HBLK_T  32768  // 64*4*16*8
#define SENT8   0xFFFFFFFFFFFFFFFFull   // 4x bf16 0xFFFF (-NaN): unreachable for finite h

typedef __attribute__((ext_vector_type(8))) short bf16x8;
typedef __attribute__((ext_vector_type(4))) float f32x4;
typedef __attribute__((ext_vector_type(4))) unsigned short us4;

static __device__ __forceinline__ unsigned short f2bf(float f) {
  union { float f; unsigned u; } v; v.f = f;
  unsigned r = v.u + 0x7FFFu + ((v.u >> 16) & 1u);  // round-to-nearest-even
  return (unsigned short)(r >> 16);
}
static __device__ __forceinline__ float bf2f(unsigned short s) {
  union { unsigned u; float f; } v; v.u = ((unsigned)s) << 16;
  return v.f;
}
static __device__ __forceinline__ float sigf(float x) { return 1.f / (1.f + __expf(-x)); }
static __device__ __forceinline__ float tanh_fast(float x) {
  x = fminf(15.f, fmaxf(-15.f, x));
  float e = __expf(2.f * x);
  return (e - 1.f) / (e + 1.f);
}

__global__ void cvt_f32_bf16(const float* __restrict__ src, unsigned short* __restrict__ dst, long n) {
  long i = (long)blockIdx.x * blockDim.x + threadIdx.x;
  long st = (long)gridDim.x * blockDim.x;
  for (; i < n; i += st) dst[i] = f2bf(src[i]);
}

__global__ void bias_sum(const float* __restrict__ a, const float* __restrict__ b,
                         float* __restrict__ o, int n) {
  int i = blockIdx.x * blockDim.x + threadIdx.x;
  if (i < n) o[i] = a[i] + b[i];
}

// One block per timestep t: stage x[.][t][.] (64x512, converted to bf16) in LDS
// once, then all 4 waves sweep the 2048 gate rows. Weights are the re-read
// item (2 MB, L2-resident). xg[t][g][b] = sum_k x[b][t][k]*W[g][k] + bias[g].
__global__ __launch_bounds__(256) void proj_kernel(
    const float* __restrict__ x,              // [B][T][D] f32
    const unsigned short* __restrict__ Wb,    // [2048][512] bf16
    const float* __restrict__ bias,           // [2048]
    unsigned short* __restrict__ xg) {
  __shared__ unsigned short xt[64 * 512];     // 64 KB, XOR-swizzled rows
  const int t   = blockIdx.x;
  const int tid = threadIdx.x;

  // stage + convert: 4096 chunks of 8 elems
  for (int i = 0; i < 16; ++i) {
    const int c    = i * 256 + tid;
    const int b    = c >> 6;
    const int col8 = c & 63;
    const float* src = x + ((long)b * T_STEPS + t) * DIN + col8 * 8;
    f32x4 v0 = *(const f32x4*)(src);
    f32x4 v1 = *(const f32x4*)(src + 4);
    union { unsigned short s[8]; bf16x8 v; } u;
    #pragma unroll
    for (int e = 0; e < 4; ++e) { u.s[e] = f2bf(v0[e]); u.s[4 + e] = f2bf(v1[e]); }
    const int byteoff = b * 1024 + ((col8 * 16) ^ ((b & 7) << 4));
    *(bf16x8*)((char*)xt + byteoff) = u.v;
  }
  __syncthreads();

  const int wv   = tid >> 6;
  const int lane = tid & 63;
  const int n16  = lane & 15;
  const int q    = lane >> 4;
  const int kof  = q * 8;

  for (int gt = 0; gt < 32; ++gt) {
    const int g0 = wv * 512 + gt * 16;
    const unsigned short* ap = Wb + (long)(g0 + n16) * DIN + kof;
    f32x4 acc[4];
    #pragma unroll
    for (int nb = 0; nb < 4; ++nb) acc[nb] = (f32x4){0.f, 0.f, 0.f, 0.f};
    #pragma unroll
    for (int kk = 0; kk < 16; ++kk) {
      bf16x8 a = *(const bf16x8*)(ap + kk * 32);
      const int colb = (kof + kk * 32) * 2;
      #pragma unroll
      for (int nb = 0; nb < 4; ++nb) {
        const int row = nb * 16 + n16;
        bf16x8 bv = *(const bf16x8*)((const char*)xt + row * 1024 + (colb ^ ((row & 7) << 4)));
        acc[nb] = __builtin_amdgcn_mfma_f32_16x16x32_bf16(a, bv, acc[nb], 0, 0, 0);
      }
    }
    const int m0 = q * 4;
    #pragma unroll
    for (int r = 0; r < 4; ++r) {
      const int g = g0 + m0 + r;
      const float bv = bias[g];
      long base = ((long)t * G4 + g) * BATCH + n16;
      xg[base +  0] = f2bf(acc[0][r] + bv);
      xg[base + 16] = f2bf(acc[1][r] + bv);
      xg[base + 32] = f2bf(acc[2][r] + bv);
      xg[base + 48] = f2bf(acc[3][r] + bv);
    }
  }
}

// Fused 2-layer dataflow recurrence. 256 WGs x 128 threads, 1 WG/CU.
// NO flags, NO fences, NO drains: h rings (T-deep, sentinel-prefilled 0xFF)
// are polled directly — a unit is valid when != SENT8 (bf16 0xFFFF = -NaN is
// unreachable for finite |h|<1). The polled loads ARE the synchronization.
__global__ __launch_bounds__(128) void fused_rec(
    const unsigned short* __restrict__ Wh0b,  // [2048][512] bf16
    const unsigned short* __restrict__ xg0,   // [T][2048][64] bf16 (bias0 folded)
    const unsigned short* __restrict__ Wx1b,  // [2048][512] bf16
    const unsigned short* __restrict__ Wh1b,  // [2048][512] bf16
    const float* __restrict__ bs1,            // [2048] = bx1+bh1
    unsigned short* __restrict__ hseq1,       // [T][64][4][16][8] bf16, 0xFF-filled
    unsigned short* __restrict__ hseq2,       // [T][64][4][16][8] bf16, 0xFF-filled
    float* __restrict__ out,                  // [64][512]
    int T) {
  __shared__ unsigned short whl0[32 * 512];    // 32 KB
  __shared__ unsigned short whl1[32 * 1024];   // 64 KB
  __shared__ __align__(16) unsigned short hsc[2][128];

  const int bid  = blockIdx.x;
  const int gq   = bid & 3;
  const int j    = bid >> 2;
  const int wv   = threadIdx.x >> 6;
  const int lane = threadIdx.x & 63;
  const int hidbase = j * 8;
  const int n16  = lane & 15;
  const int q    = lane >> 4;
  const int kof  = q * 8;
  const int bloc = q * 4;
  const int rr0 = n16, rr1 = 16 + n16;
  const int grow0 = (rr0 >> 3) * HID + hidbase + (rr0 & 7);
  const int grow1 = (rr1 >> 3) * HID + hidbase + (rr1 & 7);
  const int rdbase = gq * 128 + n16 * 8;       // ushort units
  const int myblk  = (j * 4 + gq) * 128;       // ushort units

  // ---- LDS fill ----
  if (wv == 0) {
    #pragma unroll 4
    for (int r = 0; r < 32; ++r) {
      const long grow = (long)(r >> 3) * HID + hidbase + (r & 7);
      bf16x8 v = *(const bf16x8*)(Wh0b + grow * HID + lane * 8);
      const int off = r * 1024 + ((lane * 16) ^ ((r & 7) << 4));
      *(bf16x8*)((char*)whl0 + off) = v;
    }
  } else {
    #pragma unroll 2
    for (int r = 0; r < 32; ++r) {
      const long grow = (long)(r >> 3) * HID + hidbase + (r & 7);
      bf16x8 va = *(const bf16x8*)(Wx1b + grow * HID + lane * 8);
      bf16x8 vb = *(const bf16x8*)(Wh1b + grow * HID + lane * 8);
      const int rb = r * 2048;
      *(bf16x8*)((char*)whl1 + rb + ((lane * 16) ^ ((r & 7) << 4))) = va;
      *(bf16x8*)((char*)whl1 + rb + ((1024 + lane * 16) ^ ((r & 7) << 4))) = vb;
    }
  }
  __syncthreads();  // once; the two waves decouple afterwards

  if (wv == 0) {
    // ================= layer 0 =================
    float c[4] = {0.f, 0.f, 0.f, 0.f};
    for (int t = 0; t < T; ++t) {
      us4 xv0 = *(const us4*)(xg0 + ((long)t * G4 + grow0) * BATCH + gq * 16 + bloc);
      us4 xv1 = *(const us4*)(xg0 + ((long)t * G4 + grow1) * BATCH + gq * 16 + bloc);

      f32x4 acc0 = {0.f,0.f,0.f,0.f}, acc1 = {0.f,0.f,0.f,0.f};
      if (t > 0) {
        const unsigned long long* hp = (const unsigned long long*)
            (hseq1 + (long)(t - 1) * HBLK_T + rdbase);
        unsigned long long lo[16], hi[16];
        int bad;
        do {
          bad = 0;
          #pragma unroll
          for (int kk = 0; kk < 16; ++kk) {
            const int boff = (kk * 4 + q) * 128;
            lo[kk] = __hip_atomic_load(hp + boff,     __ATOMIC_RELAXED, __HIP_MEMORY_SCOPE_AGENT);
            hi[kk] = __hip_atomic_load(hp + boff + 1, __ATOMIC_RELAXED, __HIP_MEMORY_SCOPE_AGENT);
          }
          #pragma unroll
          for (int kk = 0; kk < 16; ++kk)
            bad |= (lo[kk] == SENT8) | (hi[kk] == SENT8);
        } while (__any(bad));
        #pragma unroll
        for (int kk = 0; kk < 16; ++kk) {
          union { unsigned long long qq[2]; bf16x8 v; } u;
          u.qq[0] = lo[kk]; u.qq[1] = hi[kk];
          const int colb = (kof + kk * 32) * 2;
          bf16x8 b0 = *(const bf16x8*)((const char*)whl0 + rr0 * 1024 + (colb ^ ((rr0 & 7) << 4)));
          bf16x8 b1 = *(const bf16x8*)((const char*)whl0 + rr1 * 1024 + (colb ^ ((rr1 & 7) << 4)));
          acc0 = __builtin_amdgcn_mfma_f32_16x16x32_bf16(u.v, b0, acc0, 0, 0, 0);
          acc1 = __builtin_amdgcn_mfma_f32_16x16x32_bf16(u.v, b1, acc1, 0, 0, 0);
        }
      }
      #pragma unroll
      for (int r = 0; r < 4; ++r) { acc0[r] += bf2f(xv0[r]); acc1[r] += bf2f(xv1[r]); }

      f32x4 o0, o1;
      #pragma unroll
      for (int r = 0; r < 4; ++r) {
        o0[r] = __shfl_xor(acc0[r], 8, 64);
        o1[r] = __shfl_xor(acc1[r], 8, 64);
      }
      if (n16 < 8) {
        #pragma unroll
        for (int r = 0; r < 4; ++r) {
          const float fg = sigf(acc0[r]);
          const float ig = sigf(o0[r]);
          const float gg = tanh_fast(acc1[r]);
          const float og = sigf(o1[r]);
          const float cn = fg * c[r] + ig * gg;
          c[r] = cn;
          const float h = og * tanh_fast(cn);
          *(unsigned short*)((char*)hsc[0] + (bloc + r) * 16 + n16 * 2) = f2bf(h);
        }
      }
      asm volatile("s_waitcnt lgkmcnt(0)" ::: "memory");
      if (lane < 32) {  // 4 full 64B lines; consumers poll for arrival
        unsigned long long v8 = *(const unsigned long long*)((const char*)hsc[0] + lane * 8);
        unsigned long long* dst = (unsigned long long*)
            (hseq1 + (long)t * HBLK_T + myblk) + lane;
        __hip_atomic_store(dst, v8, __ATOMIC_RELAXED, __HIP_MEMORY_SCOPE_AGENT);
      }
      // no drain, no flag
    }
  } else {
    // ================= layer 1 =================
    float c[4] = {0.f, 0.f, 0.f, 0.f};
    const float b0v = bs1[grow0], b1v = bs1[grow1];
    for (int t = 0; t < T; ++t) {
      f32x4 acc0 = {0.f,0.f,0.f,0.f}, acc1 = {0.f,0.f,0.f,0.f};
      // ---- part A: Wx1 * h1[t] (poll hseq1[t]) ----
      {
        const unsigned long long* hp = (const unsigned long long*)
            (hseq1 + (long)t * HBLK_T + rdbase);
        unsigned long long lo[16], hi[16];
        int bad;
        do {
          bad = 0;
          #pragma unroll
          for (int kk = 0; kk < 16; ++kk) {
            const int boff = (kk * 4 + q) * 128;
            lo[kk] = __hip_atomic_load(hp + boff,     __ATOMIC_RELAXED, __HIP_MEMORY_SCOPE_AGENT);
            hi[kk] = __hip_atomic_load(hp + boff + 1, __ATOMIC_RELAXED, __HIP_MEMORY_SCOPE_AGENT);
          }
          #pragma unroll
          for (int kk = 0; kk < 16; ++kk)
            bad |= (lo[kk] == SENT8) | (hi[kk] == SENT8);
        } while (__any(bad));
        #pragma unroll
        for (int kk = 0; kk < 16; ++kk) {
          union { unsigned long long qq[2]; bf16x8 v; } u;
          u.qq[0] = lo[kk]; u.qq[1] = hi[kk];
          const int colb = (kof + kk * 32) * 2;
          bf16x8 b0 = *(const bf16x8*)((const char*)whl1 + rr0 * 2048 + (colb ^ ((rr0 & 7) << 4)));
          bf16x8 b1 = *(const bf16x8*)((const char*)whl1 + rr1 * 2048 + (colb ^ ((rr1 & 7) << 4)));
          acc0 = __builtin_amdgcn_mfma_f32_16x16x32_bf16(u.v, b0, acc0, 0, 0, 0);
          acc1 = __builtin_amdgcn_mfma_f32_16x16x32_bf16(u.v, b1, acc1, 0, 0, 0);
        }
      }
      // ---- part B: Wh1 * h2[t-1] (poll hseq2[t-1]) ----
      if (t > 0) {
        const unsigned long long* hp = (const unsigned long long*)
            (hseq2 + (long)(t - 1) * HBLK_T + rdbase);
        unsigned long long lo[16], hi[16];
        int bad;
        do {
          bad = 0;
          #pragma unroll
          for (int kk = 0; kk < 16; ++kk) {
            const int boff = (kk * 4 + q) * 128;
            lo[kk] = __hip_atomic_load(hp + boff,     __ATOMIC_RELAXED, __HIP_MEMORY_SCOPE_AGENT);
            hi[kk] = __hip_atomic_load(hp + boff + 1, __ATOMIC_RELAXED, __HIP_MEMORY_SCOPE_AGENT);
          }
          #pragma unroll
          for (int kk = 0; kk < 16; ++kk)
            bad |= (lo[kk] == SENT8) | (hi[kk] == SENT8);
        } while (__any(bad));
        #pragma unroll
        for (int kk = 0; kk < 16; ++kk) {
          union { unsigned long long qq[2]; bf16x8 v; } u;
          u.qq[0] = lo[kk]; u.qq[1] = hi[kk];
          const int colb = 1024 + (kof + kk * 32) * 2;
          bf16x8 b0 = *(const bf16x8*)((const char*)whl1 + rr0 * 2048 + (colb ^ ((rr0 & 7) << 4)));
          bf16x8 b1 = *(const bf16x8*)((const char*)whl1 + rr1 * 2048 + (colb ^ ((rr1 & 7) << 4)));
          acc0 = __builtin_amdgcn_mfma_f32_16x16x32_bf16(u.v, b0, acc0, 0, 0, 0);
          acc1 = __builtin_amdgcn_mfma_f32_16x16x32_bf16(u.v, b1, acc1, 0, 0, 0);
        }
      }
      #pragma unroll
      for (int r = 0; r < 4; ++r) { acc0[r] += b0v; acc1[r] += b1v; }

      f32x4 o0, o1;
      #pragma unroll
      for (int r = 0; r < 4; ++r) {
        o0[r] = __shfl_xor(acc0[r], 8, 64);
        o1[r] = __shfl_xor(acc1[r], 8, 64);
      }
      if (n16 < 8) {
        const int hid = hidbase + n16;
        #pragma unroll
        for (int r = 0; r < 4; ++r) {
          const float fg = sigf(acc0[r]);
          const float ig = sigf(o0[r]);
          const float gg = tanh_fast(acc1[r]);
          const float og = sigf(o1[r]);
          const float cn = fg * c[r] + ig * gg;
          c[r] = cn;
          const float h = og * tanh_fast(cn);
          *(unsigned short*)((char*)hsc[1] + (bloc + r) * 16 + n16 * 2) = f2bf(h);
          if (t == T - 1) out[(long)(gq * 16 + bloc + r) * HID + hid] = h;
        }
      }
      asm volatile("s_waitcnt lgkmcnt(0)" ::: "memory");
      if (lane < 32) {
        unsigned long long v8 = *(const unsigned long long*)((const char*)hsc[1] + lane * 8);
        unsigned long long* dst = (unsigned long long*)
            (hseq2 + (long)t * HBLK_T + myblk) + lane;
        __hip_atomic_store(dst, v8, __ATOMIC_RELAXED, __HIP_MEMORY_SCOPE_AGENT);
      }
    }
  }
}

extern "C" void kernel_launch(void* const* d_in, const int* in_sizes, int n_in,
                              void* d_out, int out_size, void* d_ws, size_t ws_size,
                              hipStream_t stream) {
  const float* x   = (const float*)d_in[0];
  const float* Wx0 = (const float*)d_in[1];
  const float* bx0 = (const float*)d_in[2];
  const float* Wh0 = (const float*)d_in[3];
  const float* bh0 = (const float*)d_in[4];
  const float* Wx1 = (const float*)d_in[5];
  const float* bx1 = (const float*)d_in[6];
  const float* Wh1 = (const float*)d_in[7];
  const float* bh1 = (const float*)d_in[8];

  char* ws = (char*)d_ws;
  size_t off = 0;
  auto alloc = [&](size_t bytes) -> char* {
    char* p = ws + off; off += (bytes + 255) & ~(size_t)255; return p;
  };
  unsigned short* xg    = (unsigned short*)alloc((size_t)T_STEPS * G4 * BATCH * 2);  // 128 MiB
  unsigned short* hseq1 = (unsigned short*)alloc((size_t)T_STEPS * HBLK_T * 2);      // 32 MiB
  unsigned short* hseq2 = (unsigned short*)alloc((size_t)T_STEPS * HBLK_T * 2);      // 32 MiB
  unsigned short* Wx0b  = (unsigned short*)alloc((size_t)G4 * DIN * 2);
  unsigned short* Wh0b  = (unsigned short*)alloc((size_t)G4 * HID * 2);
  unsigned short* Wx1b  = (unsigned short*)alloc((size_t)G4 * HID * 2);
  unsigned short* Wh1b  = (unsigned short*)alloc((size_t)G4 * HID * 2);
  float* bs0 = (float*)alloc((size_t)G4 * 4);
  float* bs1 = (float*)alloc((size_t)G4 * 4);

  // sentinel-fill the h rings (0xFF bytes = bf16 -NaN, unreachable for real h)
  hipMemsetAsync(hseq1, 0xFF, (size_t)T_STEPS * HBLK_T * 2, stream);
  hipMemsetAsync(hseq2, 0xFF, (size_t)T_STEPS * HBLK_T * 2, stream);

  cvt_f32_bf16<<<1024, 256, 0, stream>>>(Wx0, Wx0b, (long)G4 * DIN);
  cvt_f32_bf16<<<1024, 256, 0, stream>>>(Wh0, Wh0b, (long)G4 * HID);
  cvt_f32_bf16<<<1024, 256, 0, stream>>>(Wx1, Wx1b, (long)G4 * HID);
  cvt_f32_bf16<<<1024, 256, 0, stream>>>(Wh1, Wh1b, (long)G4 * HID);
  bias_sum<<<8, 256, 0, stream>>>(bx0, bh0, bs0, G4);
  bias_sum<<<8, 256, 0, stream>>>(bx1, bh1, bs1, G4);

  // layer-0 input projections: one block per timestep, x staged+converted in LDS
  proj_kernel<<<T_STEPS, 256, 0, stream>>>(x, Wx0b, bs0, xg);
  // fused dataflow 2-layer recurrence
  fused_rec<<<256, 128, 0, stream>>>(Wh0b, xg, Wx1b, Wh1b, bs1,
                                     hseq1, hseq2, (float*)d_out, T_STEPS);
}